// Round 8
// baseline (419.837 us; speedup 1.0000x reference)
//
#include <hip/hip_runtime.h>
#include <hip/hip_fp16.h>
#include <math.h>

#define BB 64
#define TT 2000
#define VV 128
#define SS 100
#define NP 1000            // row-pairs per batch: pair p holds frames 2p+1, 2p+2
#define PRB 408            // bytes per pair-row: 51 lanes * 8B
#define LN2D 0.6931471805599453
#define NRF 135            // producer fwd-side rounds per batch (pairs 0..539)
#define NRB 130            // producer bwd-side rounds per batch (pairs pL-519..pL)
#define NR  (NRF + NRB)    // 265 producer rounds per batch
#define FPS 160            // flag slots per side (padded)

// ---------------- shared helpers ----------------
__device__ __forceinline__ float wave_sum_f32(float v) {
    int t;
    t = __builtin_amdgcn_update_dpp(0, __float_as_int(v), 0x111, 0xF, 0xF, true);  v += __int_as_float(t);
    t = __builtin_amdgcn_update_dpp(0, __float_as_int(v), 0x112, 0xF, 0xF, true);  v += __int_as_float(t);
    t = __builtin_amdgcn_update_dpp(0, __float_as_int(v), 0x114, 0xF, 0xF, true);  v += __int_as_float(t);
    t = __builtin_amdgcn_update_dpp(0, __float_as_int(v), 0x118, 0xF, 0xF, true);  v += __int_as_float(t);
    t = __builtin_amdgcn_update_dpp(0, __float_as_int(v), 0x142, 0xA, 0xF, false); v += __int_as_float(t);
    t = __builtin_amdgcn_update_dpp(0, __float_as_int(v), 0x143, 0xC, 0xF, false); v += __int_as_float(t);
    return __int_as_float(__builtin_amdgcn_readlane(__float_as_int(v), 63));
}

union H4 { uint2 u; __half h[4]; };

__device__ __forceinline__ double dpp_shr1_f64(double x) {   // lane l <- l-1, lane0 -> 0
    long long bl = __double_as_longlong(x);
    int lo = (int)bl, hi = (int)(bl >> 32);
    lo = __builtin_amdgcn_update_dpp(0, lo, 0x138, 0xF, 0xF, true);
    hi = __builtin_amdgcn_update_dpp(0, hi, 0x138, 0xF, 0xF, true);
    return __longlong_as_double((long long)(((unsigned long long)(unsigned)hi << 32) | (unsigned)lo));
}

__device__ __forceinline__ double dpp_shl1_f64(double x) {   // lane l <- l+1, lane63 -> 0
    long long bl = __double_as_longlong(x);
    int lo = (int)bl, hi = (int)(bl >> 32);
    lo = __builtin_amdgcn_update_dpp(0, lo, 0x130, 0xF, 0xF, true);
    hi = __builtin_amdgcn_update_dpp(0, hi, 0x130, 0xF, 0xF, true);
    return __longlong_as_double((long long)(((unsigned long long)(unsigned)hi << 32) | (unsigned)lo));
}

__device__ __forceinline__ int wave_max_i32(int v) {
    int t;
    t = __builtin_amdgcn_update_dpp(0, v, 0x111, 0xF, 0xF, true); v = v > t ? v : t;
    t = __builtin_amdgcn_update_dpp(0, v, 0x112, 0xF, 0xF, true); v = v > t ? v : t;
    t = __builtin_amdgcn_update_dpp(0, v, 0x114, 0xF, 0xF, true); v = v > t ? v : t;
    t = __builtin_amdgcn_update_dpp(0, v, 0x118, 0xF, 0xF, true); v = v > t ? v : t;
    t = __builtin_amdgcn_update_dpp(v, v, 0x142, 0xA, 0xF, false); v = v > t ? v : t;
    t = __builtin_amdgcn_update_dpp(v, v, 0x143, 0xC, 0xF, false); v = v > t ? v : t;
    return __builtin_amdgcn_readlane(v, 63);
}

// round-6 step forms (fastest measured)
#define FSTEP(Q1, Q3) do {                                   \
    double am1 = dpp_shr1_f64(a3);                           \
    double t23 = a2 + a3;                                    \
    double n3 = fma(sk3, a1, t23) * (Q3);                    \
    double t01 = a0 + a1;                                    \
    double n1 = fma(sk1, am1, t01) * (Q1);                   \
    double n0 = a0 + am1;                                    \
    double n2 = a1 + a2;                                     \
    a0 = n0; a1 = n1; a2 = n2; a3 = n3;                      \
} while (0)

#define BSTEP(Q1, Q3) do {                                   \
    double bp0 = dpp_shl1_f64(a0);                           \
    double bp1 = dpp_shl1_f64(a1);                           \
    double t12 = a1 + a2;                                    \
    double c1 = fma(sk3, a3, t12) * (Q1);                    \
    double c0 = a0 + a1;                                     \
    double t30 = a3 + bp0;                                   \
    double c3 = fma(skB, bp1, t30) * (Q3);                   \
    double c2 = a2 + a3;                                     \
    a0 = c0; a1 = c1; a2 = c2; a3 = c3;                      \
} while (0)

#define RENORM() do {                                        \
    int h0 = (int)(__double_as_longlong(a0) >> 32);          \
    int h1 = (int)(__double_as_longlong(a1) >> 32);          \
    int h2 = (int)(__double_as_longlong(a2) >> 32);          \
    int h3 = (int)(__double_as_longlong(a3) >> 32);          \
    int m01 = h0 > h1 ? h0 : h1;                             \
    int m23 = h2 > h3 ? h2 : h3;                             \
    int mm  = wave_max_i32(m01 > m23 ? m01 : m23);           \
    int ex  = (mm >> 20) & 0x7FF;                            \
    int exc = ex > 0 ? ex : 1;                               \
    double f = __longlong_as_double((long long)(2046 - exc) << 52); \
    a0 *= f; a1 *= f; a2 *= f; a3 *= f;                      \
    Epow += exc - 1023;                                      \
} while (0)

#define CVT4(H, Q1A, Q3A, Q1B, Q3B) do {                     \
    Q1A = (double)__half2float((H).h[0]);                    \
    Q3A = (double)__half2float((H).h[1]);                    \
    Q1B = (double)__half2float((H).h[2]);                    \
    Q3B = (double)__half2float((H).h[3]); } while (0)

// lane-parallel flag wait: ensure contiguous flags [0..NEED] of ARR are set
#define WAITX(ARR, ST, NEED) do {                                           \
    while ((ST) <= (NEED)) {                                                \
        int idx_ = (ST) + lane;                                             \
        int v_ = (idx_ < FPS) ? __hip_atomic_load((ARR) + idx_,             \
                     __ATOMIC_ACQUIRE, __HIP_MEMORY_SCOPE_AGENT) : 1;       \
        unsigned long long m_ = __ballot(v_ != 0);                          \
        int adv_ = (m_ == ~0ull) ? 64 : (int)__builtin_ctzll(~m_);          \
        if (adv_ == 0) __builtin_amdgcn_s_sleep(8);                         \
        (ST) += adv_;                                                       \
    }                                                                       \
} while (0)

#define WAITALL() do {                                                      \
    while (true) {                                                          \
        int bad_ = 0;                                                       \
        for (int f_ = lane; f_ < NRF; f_ += 64)                             \
            bad_ |= (__hip_atomic_load(flagsF + f_, __ATOMIC_ACQUIRE,       \
                         __HIP_MEMORY_SCOPE_AGENT) == 0);                   \
        for (int f_ = lane; f_ < NRB; f_ += 64)                             \
            bad_ |= (__hip_atomic_load(flagsB + f_, __ATOMIC_ACQUIRE,       \
                         __HIP_MEMORY_SCOPE_AGENT) == 0);                   \
        if (__ballot(bad_ != 0) == 0ull) break;                             \
        __builtin_amdgcn_s_sleep(16);                                       \
    }                                                                       \
} while (0)

union SmemU {
    float k1sm[4][2][VV];
    struct { double SA[256]; double SC[256]; double sred[2]; int sE[2]; } k2;
};

// ================= fused producer/consumer kernel =================
__global__ __launch_bounds__(256) void ctc_fused(
    const float* __restrict__ logits, const int* __restrict__ targets,
    const int* __restrict__ in_lens, const int* __restrict__ tgt_lens,
    ushort* __restrict__ pe2, float* __restrict__ logSb,
    int* __restrict__ flags, float* __restrict__ out)
{
    __shared__ SmemU S;
    const int tid  = threadIdx.x;
    const int lane = tid & 63;
    const int wv   = tid >> 6;

    if (blockIdx.x >= 64) {
        // ---------------- producer (k1 role): one pair per wave ----------------
        const int j = blockIdx.x - 64;
        const int b = j & 63;
        const int r = j >> 6;                    // 0..NR-1; rounds dispatch ~in order
        int side, f;
        if (r < 2 * NRB) { side = r & 1; f = r >> 1; }
        else             { side = 0;     f = r - NRB; }   // fwd f = 130..134
        const int n  = in_lens[b];
        const int pL = (n - 2) >> 1;
        const int p  = (side == 0 ? 4 * f : pL - 4 * f - 3) + wv;

        if (p >= 0 && p < NP) {
            const int tA = 2 * p + 1, tB = 2 * p + 2;
            const bool vB = (tB < TT);
            const float2* rA = reinterpret_cast<const float2*>(logits + ((size_t)b * TT + tA) * VV);
            const float2* rB = reinterpret_cast<const float2*>(logits + ((size_t)b * TT + (vB ? tB : tA)) * VV);
            float2 xa = rA[lane], xb = rB[lane];

            float ea0 = __expf(xa.x), ea1 = __expf(xa.y);
            float eb0 = __expf(xb.x), eb1 = __expf(xb.y);
            float sa = wave_sum_f32(ea0 + ea1);
            float sb = wave_sum_f32(eb0 + eb1);

            float* sm0 = S.k1sm[wv][0];
            float* sm1 = S.k1sm[wv][1];
            sm0[2 * lane] = ea0; sm0[2 * lane + 1] = ea1;
            sm1[2 * lane] = eb0; sm1[2 * lane + 1] = eb1;
            // producer/consumer are the SAME wave: no barrier needed

            int tg0 = 0, tg1 = 0;
            if (lane < 50) {
                int2 tg = reinterpret_cast<const int2*>(targets)[b * (SS / 2) + lane];
                tg0 = tg.x; tg1 = tg.y;
            }
            const float qiA = 1.0f / sm0[0];
            const float qiB = 1.0f / sm1[0];
            float q1a = 0.f, q3a = 0.f, q1b = 0.f, q3b = 0.f;
            if (lane < 50) {
                q1a = fminf(sm0[tg0] * qiA, 65504.f);
                q3a = fminf(sm0[tg1] * qiA, 65504.f);
                if (vB) {
                    q1b = fminf(sm1[tg0] * qiB, 65504.f);
                    q3b = fminf(sm1[tg1] * qiB, 65504.f);
                }
            }
            if (lane < 51) {
                ushort4 w;
                w.x = __half_as_ushort(__float2half_rn(q1a));
                w.y = __half_as_ushort(__float2half_rn(q3a));
                w.z = __half_as_ushort(__float2half_rn(q1b));
                w.w = __half_as_ushort(__float2half_rn(q3b));
                *reinterpret_cast<ushort4*>((char*)pe2 + ((size_t)b * NP + p) * PRB + lane * 8) = w;
            }
            if (lane == 0) {
                logSb[b * TT + tA] = __logf(sa) - xa.x;
                if (vB) logSb[b * TT + tB] = __logf(sb) - xb.x;
            }
        }
        __syncthreads();   // drains all 4 waves' stores (vmcnt) before flag
        if (tid == 0)
            __hip_atomic_store(&flags[(b * 2 + side) * FPS + f], 1,
                               __ATOMIC_RELEASE, __HIP_MEMORY_SCOPE_AGENT);
        return;
    }

    // ---------------- consumer (k2 role): 2 scan waves per batch ----------------
    const int b    = blockIdx.x;
    const int n    = in_lens[b];
    const int tl   = tgt_lens[b];
    const int P    = (13 * (n - 2)) / 50;
    const int pL   = (n - 2) >> 1;

    const int* flagsF = flags + (b * 2 + 0) * FPS;
    const int* flagsB = flags + (b * 2 + 1) * FPS;

    int tg0 = 0, tg1 = 0, tgm1 = 0, tg2 = 0;
    if (lane < 50) {
        int2 tg = reinterpret_cast<const int2*>(targets)[b * (SS / 2) + lane];
        tg0 = tg.x; tg1 = tg.y;
    }
    if (lane >= 1 && lane <= 50) tgm1 = targets[b * SS + 2 * lane - 1];
    if (lane <= 48) tg2 = targets[b * SS + 2 * lane + 2];
    const double sk1 = (tg0 != tgm1) ? 1.0 : 0.0;
    const double sk3 = (tg1 != tg0)  ? 1.0 : 0.0;
    const double skB = (tg2 != tg1)  ? 1.0 : 0.0;

    const int cl = (lane < 51) ? lane : 50;
    const char* PBbase = (const char*)pe2 + (size_t)b * NP * PRB + (size_t)cl * 8;

    double a0 = 0.0, a1 = 0.0, a2 = 0.0, a3 = 0.0;
    int Epow = 0;
    double lsb0 = 0.0;
    uint2 buf[16];

    if (wv == 0) {
        // frame-0 prologue from logits
        float2 x0 = reinterpret_cast<const float2*>(logits + (size_t)b * TT * VV)[lane];
        float e00 = __expf(x0.x), e01 = __expf(x0.y);
        float s0v = wave_sum_f32(e00 + e01);
        float qb0 = __shfl(e00, 0);
        int ext1 = targets[b * SS];
        float qn = __shfl((ext1 & 1) ? e01 : e00, ext1 >> 1);
        if (lane == 0) {
            a0 = 1.0;
            if (tl > 0) a1 = (double)qn / (double)qb0;
            lsb0 = (double)__logf(s0v) - (double)x0.x;
        }

        int fR = 0;
        WAITX(flagsF, fR, 3);
        #pragma unroll
        for (int d = 0; d < 16; ++d)
            buf[d] = *reinterpret_cast<const uint2*>(PBbase + (size_t)d * PRB);
        const char* Pc = PBbase + (size_t)16 * PRB;
        double c1A, c3A, c1B, c3B, n1A, n3A, n1B, n3B;
        { H4 h0; h0.u = buf[0]; CVT4(h0, c1A, c3A, c1B, c3B); }
        const int nfull = P >> 4, rem = P & 15;
        for (int c = 0; c < nfull; ++c) {
            WAITX(flagsF, fR, 4 * c + 7);
            #pragma unroll
            for (int d = 0; d < 16; ++d) {
                H4 hn; hn.u = buf[(d + 1) & 15];
                buf[d] = *reinterpret_cast<const uint2*>(Pc + (size_t)d * PRB);
                CVT4(hn, n1A, n3A, n1B, n3B);
                FSTEP(c1A, c3A);
                FSTEP(c1B, c3B);
                c1A = n1A; c3A = n3A; c1B = n1B; c3B = n3B;
            }
            RENORM();
            Pc += (size_t)16 * PRB;
        }
        #pragma unroll
        for (int d = 0; d < 16; ++d) {
            if (d < rem) {
                H4 h; h.u = buf[d];
                double q1A, q3A, q1B, q3B; CVT4(h, q1A, q3A, q1B, q3B);
                FSTEP(q1A, q3A);
                FSTEP(q1B, q3B);
            }
        }
        RENORM();
        S.k2.SA[4 * lane + 0] = a0; S.k2.SA[4 * lane + 1] = a1;
        S.k2.SA[4 * lane + 2] = a2; S.k2.SA[4 * lane + 3] = a3;
        if (lane == 0) S.k2.sE[0] = Epow;
    } else if (wv == 1) {
        int bR = 0;
        WAITX(flagsB, bR, 0);
        H4 hi; hi.u = *reinterpret_cast<const uint2*>(PBbase + (size_t)pL * PRB);
        const bool nOdd = (n & 1);
        double q1i = (double)__half2float(nOdd ? hi.h[2] : hi.h[0]);
        double q3i = (double)__half2float(nOdd ? hi.h[3] : hi.h[1]);
        const int s2 = 2 * tl, s1 = 2 * tl - 1;
        a0 = (4 * lane     == s2) ? 1.0 : 0.0;
        a1 = (4 * lane + 1 == s1) ? q1i : 0.0;
        a2 = (4 * lane + 2 == s2) ? 1.0 : 0.0;
        a3 = (4 * lane + 3 == s1) ? q3i : 0.0;
        if (nOdd) {
            double q1 = (double)__half2float(hi.h[0]);
            double q3 = (double)__half2float(hi.h[1]);
            BSTEP(q1, q3);
        }

        const int NB = pL - P;
        WAITX(flagsB, bR, 4);
        #pragma unroll
        for (int d = 0; d < 16; ++d)
            buf[d] = *reinterpret_cast<const uint2*>(PBbase + (size_t)(pL - 1 - d) * PRB);
        const char* Pc = PBbase + (size_t)(pL - 1 - 16) * PRB;
        double c1A, c3A, c1B, c3B, n1A, n3A, n1B, n3B;
        { H4 h0; h0.u = buf[0]; CVT4(h0, c1A, c3A, c1B, c3B); }
        const int nfull = NB >> 4, rem = NB & 15;
        for (int c = 0; c < nfull; ++c) {
            WAITX(flagsB, bR, 4 * c + 8);
            #pragma unroll
            for (int d = 0; d < 16; ++d) {
                H4 hn; hn.u = buf[(d + 1) & 15];
                buf[d] = *reinterpret_cast<const uint2*>(Pc - (size_t)d * PRB);
                CVT4(hn, n1A, n3A, n1B, n3B);
                BSTEP(c1B, c3B);
                BSTEP(c1A, c3A);
                c1A = n1A; c3A = n3A; c1B = n1B; c3B = n3B;
            }
            RENORM();
            Pc -= (size_t)16 * PRB;
        }
        #pragma unroll
        for (int d = 0; d < 16; ++d) {
            if (d < rem) {
                H4 h; h.u = buf[d];
                double q1A, q3A, q1B, q3B; CVT4(h, q1A, q3A, q1B, q3B);
                BSTEP(q1B, q3B);
                BSTEP(q1A, q3A);
            }
        }
        RENORM();
        {
            double bp0 = dpp_shl1_f64(a0);
            double bp1 = dpp_shl1_f64(a1);
            double c0 = a0 + a1;
            double c1 = fma(sk3, a3, a1 + a2);
            double c2 = a2 + a3;
            double c3 = fma(skB, bp1, a3 + bp0);
            S.k2.SC[4 * lane + 0] = c0; S.k2.SC[4 * lane + 1] = c1;
            S.k2.SC[4 * lane + 2] = c2; S.k2.SC[4 * lane + 3] = c3;
        }
        if (lane == 0) S.k2.sE[1] = Epow;
    }

    if (wv < 2) {
        WAITALL();   // all logSb frames produced
        double cb = 0.0;
        for (int t = 1 + tid; t < n; t += 128) cb += (double)logSb[b * TT + t];
        #pragma unroll
        for (int off = 32; off; off >>= 1) cb += __shfl_xor(cb, off);
        if (lane == 0) S.k2.sred[wv] = cb;
    }

    __syncthreads();

    if (wv == 0) {
        double d0 = S.k2.SA[4 * lane + 0] * S.k2.SC[4 * lane + 0]
                  + S.k2.SA[4 * lane + 1] * S.k2.SC[4 * lane + 1]
                  + S.k2.SA[4 * lane + 2] * S.k2.SC[4 * lane + 2]
                  + S.k2.SA[4 * lane + 3] * S.k2.SC[4 * lane + 3];
        #pragma unroll
        for (int off = 32; off; off >>= 1) d0 += __shfl_xor(d0, off);
        if (lane == 0) {
            double dot = d0;
            int extraE = 0;
            long long bits = __double_as_longlong(dot);
            int be = (int)((bits >> 52) & 0x7FF);
            if (be == 0) {
                dot *= 0x1.0p+512;
                bits = __double_as_longlong(dot);
                be = (int)((bits >> 52) & 0x7FF);
                extraE = -512;
            }
            double mant = __longlong_as_double((bits & 0xFFFFFFFFFFFFFLL) | 0x3FF0000000000000LL);
            double logdot = ((double)(be - 1023 + extraE + S.k2.sE[0] + S.k2.sE[1])) * LN2D
                          + (double)__logf((float)mant);
            double loss = (S.k2.sred[0] + S.k2.sred[1] + lsb0) - logdot;
            atomicAdd(out, (float)loss);
        }
    }
}

extern "C" void kernel_launch(void* const* d_in, const int* in_sizes, int n_in,
                              void* d_out, int out_size, void* d_ws, size_t ws_size,
                              hipStream_t stream)
{
    const float* logits  = (const float*)d_in[0];
    const int* targets   = (const int*)d_in[1];
    const int* in_lens   = (const int*)d_in[2];
    const int* tgt_lens  = (const int*)d_in[3];
    float* out = (float*)d_out;

    ushort* pe2  = (ushort*)d_ws;
    float* logSb = (float*)((char*)d_ws + (size_t)BB * NP * PRB);                    // 26,112,000
    int*   flags = (int*)((char*)d_ws + (size_t)BB * NP * PRB + BB * TT * 4);        // +512,000

    hipMemsetAsync(d_out, 0, sizeof(float), stream);
    hipMemsetAsync(flags, 0, (size_t)BB * 2 * FPS * sizeof(int), stream);
    ctc_fused<<<64 + BB * NR, 256, 0, stream>>>(logits, targets, in_lens, tgt_lens,
                                                pe2, logSb, flags, out);
}

// Round 9
// 133.428 us; speedup vs baseline: 3.1466x; 3.1466x over previous
//
#include <hip/hip_runtime.h>
#include <hip/hip_fp16.h>
#include <math.h>

#define BB 64
#define TT 2000
#define VV 128
#define SS 100
#define NP 1000            // row-pairs per batch: pair p holds frames 2p+1, 2p+2
#define PRB 448            // bytes per pair-row: 51 lanes * 8B, padded to 7 cache lines
#define LN2D 0.6931471805599453
#define SENT (1 << 26)

// ---- coherent (agent-scope, relaxed — no fences/flushes) access helpers ----
__device__ __forceinline__ void cstore8(void* p, unsigned long long v) {
    __hip_atomic_store((unsigned long long*)p, v, __ATOMIC_RELAXED, __HIP_MEMORY_SCOPE_AGENT);
}
__device__ __forceinline__ void cstoref(float* p, float v) {
    __hip_atomic_store(p, v, __ATOMIC_RELAXED, __HIP_MEMORY_SCOPE_AGENT);
}
__device__ __forceinline__ void cstorei(int* p, int v) {
    __hip_atomic_store(p, v, __ATOMIC_RELAXED, __HIP_MEMORY_SCOPE_AGENT);
}
__device__ __forceinline__ int cloadi(const int* p) {
    return __hip_atomic_load(p, __ATOMIC_RELAXED, __HIP_MEMORY_SCOPE_AGENT);
}

__device__ __forceinline__ float wave_sum_f32(float v) {
    int t;
    t = __builtin_amdgcn_update_dpp(0, __float_as_int(v), 0x111, 0xF, 0xF, true);  v += __int_as_float(t);
    t = __builtin_amdgcn_update_dpp(0, __float_as_int(v), 0x112, 0xF, 0xF, true);  v += __int_as_float(t);
    t = __builtin_amdgcn_update_dpp(0, __float_as_int(v), 0x114, 0xF, 0xF, true);  v += __int_as_float(t);
    t = __builtin_amdgcn_update_dpp(0, __float_as_int(v), 0x118, 0xF, 0xF, true);  v += __int_as_float(t);
    t = __builtin_amdgcn_update_dpp(0, __float_as_int(v), 0x142, 0xA, 0xF, false); v += __int_as_float(t);
    t = __builtin_amdgcn_update_dpp(0, __float_as_int(v), 0x143, 0xC, 0xF, false); v += __int_as_float(t);
    return __int_as_float(__builtin_amdgcn_readlane(__float_as_int(v), 63));
}

union H4 { uint2 u; __half h[4]; };

__device__ __forceinline__ double dpp_shr1_f64(double x) {   // lane l <- l-1, lane0 -> 0
    long long bl = __double_as_longlong(x);
    int lo = (int)bl, hi = (int)(bl >> 32);
    lo = __builtin_amdgcn_update_dpp(0, lo, 0x138, 0xF, 0xF, true);
    hi = __builtin_amdgcn_update_dpp(0, hi, 0x138, 0xF, 0xF, true);
    return __longlong_as_double((long long)(((unsigned long long)(unsigned)hi << 32) | (unsigned)lo));
}

__device__ __forceinline__ double dpp_shl1_f64(double x) {   // lane l <- l+1, lane63 -> 0
    long long bl = __double_as_longlong(x);
    int lo = (int)bl, hi = (int)(bl >> 32);
    lo = __builtin_amdgcn_update_dpp(0, lo, 0x130, 0xF, 0xF, true);
    hi = __builtin_amdgcn_update_dpp(0, hi, 0x130, 0xF, 0xF, true);
    return __longlong_as_double((long long)(((unsigned long long)(unsigned)hi << 32) | (unsigned)lo));
}

__device__ __forceinline__ int wave_max_i32(int v) {
    int t;
    t = __builtin_amdgcn_update_dpp(0, v, 0x111, 0xF, 0xF, true); v = v > t ? v : t;
    t = __builtin_amdgcn_update_dpp(0, v, 0x112, 0xF, 0xF, true); v = v > t ? v : t;
    t = __builtin_amdgcn_update_dpp(0, v, 0x114, 0xF, 0xF, true); v = v > t ? v : t;
    t = __builtin_amdgcn_update_dpp(0, v, 0x118, 0xF, 0xF, true); v = v > t ? v : t;
    t = __builtin_amdgcn_update_dpp(v, v, 0x142, 0xA, 0xF, false); v = v > t ? v : t;
    t = __builtin_amdgcn_update_dpp(v, v, 0x143, 0xC, 0xF, false); v = v > t ? v : t;
    return __builtin_amdgcn_readlane(v, 63);
}

#define FSTEP(Q1, Q3) do {                                   \
    double am1 = dpp_shr1_f64(a3);                           \
    double t23 = a2 + a3;                                    \
    double n3 = fma(sk3, a1, t23) * (Q3);                    \
    double t01 = a0 + a1;                                    \
    double n1 = fma(sk1, am1, t01) * (Q1);                   \
    double n0 = a0 + am1;                                    \
    double n2 = a1 + a2;                                     \
    a0 = n0; a1 = n1; a2 = n2; a3 = n3;                      \
} while (0)

#define BSTEP(Q1, Q3) do {                                   \
    double bp0 = dpp_shl1_f64(a0);                           \
    double bp1 = dpp_shl1_f64(a1);                           \
    double t12 = a1 + a2;                                    \
    double c1 = fma(sk3, a3, t12) * (Q1);                    \
    double c0 = a0 + a1;                                     \
    double t30 = a3 + bp0;                                   \
    double c3 = fma(skB, bp1, t30) * (Q3);                   \
    double c2 = a2 + a3;                                     \
    a0 = c0; a1 = c1; a2 = c2; a3 = c3;                      \
} while (0)

#define RENORM() do {                                        \
    int h0 = (int)(__double_as_longlong(a0) >> 32);          \
    int h1 = (int)(__double_as_longlong(a1) >> 32);          \
    int h2 = (int)(__double_as_longlong(a2) >> 32);          \
    int h3 = (int)(__double_as_longlong(a3) >> 32);          \
    int m01 = h0 > h1 ? h0 : h1;                             \
    int m23 = h2 > h3 ? h2 : h3;                             \
    int mm  = wave_max_i32(m01 > m23 ? m01 : m23);           \
    int ex  = (mm >> 20) & 0x7FF;                            \
    int exc = ex > 0 ? ex : 1;                               \
    double f = __longlong_as_double((long long)(2046 - exc) << 52); \
    a0 *= f; a1 *= f; a2 *= f; a3 *= f;                      \
    Epow += exc - 1023;                                      \
} while (0)

#define CVT4(H, Q1A, Q3A, Q1B, Q3B) do {                     \
    Q1A = (double)__half2float((H).h[0]);                    \
    Q3A = (double)__half2float((H).h[1]);                    \
    Q1B = (double)__half2float((H).h[2]);                    \
    Q3B = (double)__half2float((H).h[3]); } while (0)

// wait until all 4 per-wave stream counters >= NEED (relaxed polls, no cache flushes)
#define WMIN4(CTR, NEED) do {                                           \
    while (true) {                                                      \
        int v_ = (lane < 4) ? cloadi((CTR) + lane) : 0x7FFFFFFF;        \
        if (__ballot(v_ < (NEED)) == 0ull) break;                       \
        __builtin_amdgcn_s_sleep(2);                                    \
    }                                                                   \
    asm volatile("" ::: "memory");                                      \
} while (0)

union SmemU {
    float k1sm[4][2][VV];
    struct { double SA[256]; double SC[256]; double sred[2]; int sE[2]; } k2;
};

// ================= fused persistent producer/consumer kernel =================
__global__ __launch_bounds__(256) void ctc_fused(
    const float* __restrict__ logits, const int* __restrict__ targets,
    const int* __restrict__ in_lens, const int* __restrict__ tgt_lens,
    ushort* __restrict__ pe2, float* __restrict__ logSb,
    int* __restrict__ flags, float* __restrict__ out)
{
    __shared__ SmemU S;
    const int tid  = threadIdx.x;
    const int lane = tid & 63;
    const int wv   = tid >> 6;

    if (blockIdx.x >= BB) {
        // ---------------- persistent producer: one block per (batch, side) ----------------
        const int j    = blockIdx.x - BB;
        const int side = j >> 6;              // 0 = fwd stream, 1 = bwd stream
        const int b    = j & 63;              // same XCD as consumer block b (both ≡ b mod 8)
        const int n    = in_lens[b];
        const int pL   = (n - 2) >> 1;
        const int P    = (13 * (n - 2)) / 50;
        const int PF_END = min(pL + 1, P + 16);
        int PB_LO = P - 33; if (PB_LO < 0) PB_LO = 0;
        int* ctr = flags + b * 32 + side * 16 + wv;

        int tg0 = 0, tg1 = 0;
        if (lane < 50) {
            int2 tg = reinterpret_cast<const int2*>(targets)[b * (SS / 2) + lane];
            tg0 = tg.x; tg1 = tg.y;
        }
        float* sm0 = S.k1sm[wv][0];
        float* sm1 = S.k1sm[wv][1];

        const int dstep = side ? -4 : 4;
        int p = side ? (pL - wv) : wv;        // wave wv owns every 4th pair, in consumption order
        const int nit = side ? ((pL - wv - PB_LO + 4) >> 2)
                             : ((PF_END - wv + 3) >> 2);

        float2 xa, xb;
        {
            int tA = 2 * p + 1, tB = 2 * p + 2; bool vB = tB < TT;
            xa = reinterpret_cast<const float2*>(logits + ((size_t)b * TT + tA) * VV)[lane];
            xb = reinterpret_cast<const float2*>(logits + ((size_t)b * TT + (vB ? tB : tA)) * VV)[lane];
        }
        for (int k = 1; k <= nit; ++k) {
            const int pc = p;
            const int tA = 2 * pc + 1, tB = 2 * pc + 2;
            const bool vB = tB < TT;
            p += dstep;
            float2 xa2, xb2;
            if (k < nit) {                    // prefetch next iteration's logits rows
                int tA2 = 2 * p + 1, tB2 = 2 * p + 2; bool vB2 = tB2 < TT;
                xa2 = reinterpret_cast<const float2*>(logits + ((size_t)b * TT + tA2) * VV)[lane];
                xb2 = reinterpret_cast<const float2*>(logits + ((size_t)b * TT + (vB2 ? tB2 : tA2)) * VV)[lane];
            }
            float ea0 = __expf(xa.x), ea1 = __expf(xa.y);
            float eb0 = __expf(xb.x), eb1 = __expf(xb.y);
            float sa = wave_sum_f32(ea0 + ea1);
            float sb = wave_sum_f32(eb0 + eb1);
            sm0[2 * lane] = ea0; sm0[2 * lane + 1] = ea1;
            sm1[2 * lane] = eb0; sm1[2 * lane + 1] = eb1;
            // same-wave LDS producer/consumer: no barrier needed
            float qiA = 1.0f / sm0[0], qiB = 1.0f / sm1[0];
            float q1a = 0.f, q3a = 0.f, q1b = 0.f, q3b = 0.f;
            if (lane < 50) {
                q1a = fminf(sm0[tg0] * qiA, 65504.f);
                q3a = fminf(sm0[tg1] * qiA, 65504.f);
                if (vB) {
                    q1b = fminf(sm1[tg0] * qiB, 65504.f);
                    q3b = fminf(sm1[tg1] * qiB, 65504.f);
                }
            }
            if (lane < 51) {
                unsigned long long v =
                      (unsigned long long)__half_as_ushort(__float2half_rn(q1a))
                    | ((unsigned long long)__half_as_ushort(__float2half_rn(q3a)) << 16)
                    | ((unsigned long long)__half_as_ushort(__float2half_rn(q1b)) << 32)
                    | ((unsigned long long)__half_as_ushort(__float2half_rn(q3b)) << 48);
                cstore8((char*)pe2 + ((size_t)b * NP + pc) * PRB + (size_t)lane * 8, v);
            }
            if (lane == 0) {
                cstoref(logSb + b * TT + tA, __logf(sa) - xa.x);
                if (vB) cstoref(logSb + b * TT + tB, __logf(sb) - xb.x);
            }
            xa = xa2; xb = xb2;
            if ((k & 3) == 0) {               // hand-rolled release: drain sc-coherent stores, then flag
                __builtin_amdgcn_s_waitcnt(0);
                asm volatile("" ::: "memory");
                cstorei(ctr, k);
            }
        }
        __builtin_amdgcn_s_waitcnt(0);
        asm volatile("" ::: "memory");
        cstorei(ctr, SENT);
        return;
    }

    // ---------------- consumer block b: wv0 fwd scan, wv1 bwd scan, wv2/3 logSb sum ----------------
    const int b  = blockIdx.x;
    const int n  = in_lens[b];
    const int tl = tgt_lens[b];
    const int P  = (13 * (n - 2)) / 50;
    const int pL = (n - 2) >> 1;
    const int* ctrF = flags + b * 32;
    const int* ctrB = flags + b * 32 + 16;

    double lsb0 = 0.0;

    if (wv >= 2) {
        // wait for both streams fully produced, then sum logSb (off scan critical path)
        while (true) {
            int v = 0x7FFFFFFF;
            if (lane < 4) v = cloadi(ctrF + lane);
            else if (lane < 8) v = cloadi(ctrB + lane - 4);
            if (__ballot(v < SENT) == 0ull) break;
            __builtin_amdgcn_s_sleep(8);
        }
        asm volatile("" ::: "memory");
        double cb = 0.0;
        for (int t = 1 + (tid & 127); t < n; t += 128) cb += (double)logSb[b * TT + t];
        #pragma unroll
        for (int off = 32; off; off >>= 1) cb += __shfl_xor(cb, off);
        if (lane == 0) S.k2.sred[wv - 2] = cb;
    } else {
        int tg0 = 0, tg1 = 0, tgm1 = 0, tg2 = 0;
        if (lane < 50) {
            int2 tg = reinterpret_cast<const int2*>(targets)[b * (SS / 2) + lane];
            tg0 = tg.x; tg1 = tg.y;
        }
        if (lane >= 1 && lane <= 50) tgm1 = targets[b * SS + 2 * lane - 1];
        if (lane <= 48) tg2 = targets[b * SS + 2 * lane + 2];
        const double sk1 = (tg0 != tgm1) ? 1.0 : 0.0;
        const double sk3 = (tg1 != tg0)  ? 1.0 : 0.0;
        const double skB = (tg2 != tg1)  ? 1.0 : 0.0;

        const int cl = (lane < 51) ? lane : 50;
        const char* PBbase = (const char*)pe2 + (size_t)b * NP * PRB + (size_t)cl * 8;

        double a0 = 0.0, a1 = 0.0, a2 = 0.0, a3 = 0.0;
        int Epow = 0;
        uint2 buf[16];

        if (wv == 0) {
            // frame-0 prologue from logits
            float2 x0 = reinterpret_cast<const float2*>(logits + (size_t)b * TT * VV)[lane];
            float e00 = __expf(x0.x), e01 = __expf(x0.y);
            float s0v = wave_sum_f32(e00 + e01);
            float qb0 = __shfl(e00, 0);
            int ext1 = targets[b * SS];
            float qn = __shfl((ext1 & 1) ? e01 : e00, ext1 >> 1);
            if (lane == 0) {
                a0 = 1.0;
                if (tl > 0) a1 = (double)qn / (double)qb0;
                lsb0 = (double)__logf(s0v) - (double)x0.x;
            }

            WMIN4(ctrF, 8);                   // pairs 0..31 produced
            #pragma unroll
            for (int d = 0; d < 16; ++d)
                buf[d] = *reinterpret_cast<const uint2*>(PBbase + (size_t)d * PRB);
            const char* Pc = PBbase + (size_t)16 * PRB;
            double c1A, c3A, c1B, c3B, n1A, n3A, n1B, n3B;
            { H4 h0; h0.u = buf[0]; CVT4(h0, c1A, c3A, c1B, c3B); }
            const int nfull = P >> 4, rem = P & 15;
            for (int c = 0; c < nfull; ++c) {
                if (c) WMIN4(ctrF, 4 * c + 8);
                #pragma unroll
                for (int d = 0; d < 16; ++d) {
                    H4 hn; hn.u = buf[(d + 1) & 15];
                    buf[d] = *reinterpret_cast<const uint2*>(Pc + (size_t)d * PRB);
                    CVT4(hn, n1A, n3A, n1B, n3B);
                    FSTEP(c1A, c3A);
                    FSTEP(c1B, c3B);
                    c1A = n1A; c3A = n3A; c1B = n1B; c3B = n3B;
                }
                RENORM();
                Pc += (size_t)16 * PRB;
            }
            #pragma unroll
            for (int d = 0; d < 16; ++d) {
                if (d < rem) {
                    H4 h; h.u = buf[d];
                    double q1A, q3A, q1B, q3B; CVT4(h, q1A, q3A, q1B, q3B);
                    FSTEP(q1A, q3A);
                    FSTEP(q1B, q3B);
                }
            }
            RENORM();
            S.k2.SA[4 * lane + 0] = a0; S.k2.SA[4 * lane + 1] = a1;
            S.k2.SA[4 * lane + 2] = a2; S.k2.SA[4 * lane + 3] = a3;
            if (lane == 0) S.k2.sE[0] = Epow;
        } else {
            WMIN4(ctrB, 12);                  // pairs pL..pL-32 produced (granularity-rounded)
            H4 hi; hi.u = *reinterpret_cast<const uint2*>(PBbase + (size_t)pL * PRB);
            const bool nOdd = (n & 1);
            double q1i = (double)__half2float(nOdd ? hi.h[2] : hi.h[0]);
            double q3i = (double)__half2float(nOdd ? hi.h[3] : hi.h[1]);
            const int s2 = 2 * tl, s1 = 2 * tl - 1;
            a0 = (4 * lane     == s2) ? 1.0 : 0.0;
            a1 = (4 * lane + 1 == s1) ? q1i : 0.0;
            a2 = (4 * lane + 2 == s2) ? 1.0 : 0.0;
            a3 = (4 * lane + 3 == s1) ? q3i : 0.0;
            if (nOdd) {
                double q1 = (double)__half2float(hi.h[0]);
                double q3 = (double)__half2float(hi.h[1]);
                BSTEP(q1, q3);
            }

            const int NB = pL - P;
            #pragma unroll
            for (int d = 0; d < 16; ++d)
                buf[d] = *reinterpret_cast<const uint2*>(PBbase + (size_t)(pL - 1 - d) * PRB);
            const char* Pc = PBbase + (size_t)(pL - 1 - 16) * PRB;
            double c1A, c3A, c1B, c3B, n1A, n3A, n1B, n3B;
            { H4 h0; h0.u = buf[0]; CVT4(h0, c1A, c3A, c1B, c3B); }
            const int nfull = NB >> 4, rem = NB & 15;
            for (int c = 0; c < nfull; ++c) {
                if (c) WMIN4(ctrB, 4 * c + 9);
                #pragma unroll
                for (int d = 0; d < 16; ++d) {
                    H4 hn; hn.u = buf[(d + 1) & 15];
                    buf[d] = *reinterpret_cast<const uint2*>(Pc - (size_t)d * PRB);
                    CVT4(hn, n1A, n3A, n1B, n3B);
                    BSTEP(c1B, c3B);
                    BSTEP(c1A, c3A);
                    c1A = n1A; c3A = n3A; c1B = n1B; c3B = n3B;
                }
                RENORM();
                Pc -= (size_t)16 * PRB;
            }
            #pragma unroll
            for (int d = 0; d < 16; ++d) {
                if (d < rem) {
                    H4 h; h.u = buf[d];
                    double q1A, q3A, q1B, q3B; CVT4(h, q1A, q3A, q1B, q3B);
                    BSTEP(q1B, q3B);
                    BSTEP(q1A, q3A);
                }
            }
            RENORM();
            {
                double bp0 = dpp_shl1_f64(a0);
                double bp1 = dpp_shl1_f64(a1);
                double c0 = a0 + a1;
                double c1 = fma(sk3, a3, a1 + a2);
                double c2 = a2 + a3;
                double c3 = fma(skB, bp1, a3 + bp0);
                S.k2.SC[4 * lane + 0] = c0; S.k2.SC[4 * lane + 1] = c1;
                S.k2.SC[4 * lane + 2] = c2; S.k2.SC[4 * lane + 3] = c3;
            }
            if (lane == 0) S.k2.sE[1] = Epow;
        }
    }

    __syncthreads();

    if (wv == 0) {
        double d0 = S.k2.SA[4 * lane + 0] * S.k2.SC[4 * lane + 0]
                  + S.k2.SA[4 * lane + 1] * S.k2.SC[4 * lane + 1]
                  + S.k2.SA[4 * lane + 2] * S.k2.SC[4 * lane + 2]
                  + S.k2.SA[4 * lane + 3] * S.k2.SC[4 * lane + 3];
        #pragma unroll
        for (int off = 32; off; off >>= 1) d0 += __shfl_xor(d0, off);
        if (lane == 0) {
            double dot = d0;
            int extraE = 0;
            long long bits = __double_as_longlong(dot);
            int be = (int)((bits >> 52) & 0x7FF);
            if (be == 0) {
                dot *= 0x1.0p+512;
                bits = __double_as_longlong(dot);
                be = (int)((bits >> 52) & 0x7FF);
                extraE = -512;
            }
            double mant = __longlong_as_double((bits & 0xFFFFFFFFFFFFFLL) | 0x3FF0000000000000LL);
            double logdot = ((double)(be - 1023 + extraE + S.k2.sE[0] + S.k2.sE[1])) * LN2D
                          + (double)__logf((float)mant);
            double loss = (S.k2.sred[0] + S.k2.sred[1] + lsb0) - logdot;
            atomicAdd(out, (float)loss);
        }
    }
}

extern "C" void kernel_launch(void* const* d_in, const int* in_sizes, int n_in,
                              void* d_out, int out_size, void* d_ws, size_t ws_size,
                              hipStream_t stream)
{
    const float* logits  = (const float*)d_in[0];
    const int* targets   = (const int*)d_in[1];
    const int* in_lens   = (const int*)d_in[2];
    const int* tgt_lens  = (const int*)d_in[3];
    float* out = (float*)d_out;

    ushort* pe2  = (ushort*)d_ws;                                        // 64*1000*448 = 28,672,000 B
    float* logSb = (float*)((char*)d_ws + (size_t)BB * NP * PRB);        // +512,000 B
    int*   flags = (int*)((char*)d_ws + (size_t)BB * NP * PRB + (size_t)BB * TT * 4); // +8,192 B

    hipMemsetAsync(d_out, 0, sizeof(float), stream);
    hipMemsetAsync(flags, 0, (size_t)BB * 32 * sizeof(int), stream);
    ctc_fused<<<BB + 128, 256, 0, stream>>>(logits, targets, in_lens, tgt_lens,
                                            pe2, logSb, flags, out);
}

// Round 11
// 65.867 us; speedup vs baseline: 6.3740x; 2.0257x over previous
//
#include <hip/hip_runtime.h>
#include <hip/hip_fp16.h>
#include <math.h>

#define BB 64
#define TT 2000
#define VV 128
#define SS 100
#define NP 1000            // row-pairs per batch: pair p holds frames 2p+1, 2p+2
#define PRB 448            // bytes per pair-row: 56 lanes * 8B = exactly 7 cache lines
#define LN2D 0.6931471805599453

// wave-wide f32 sum via DPP; result uniform via readlane
__device__ __forceinline__ float wave_sum_f32(float v) {
    int t;
    t = __builtin_amdgcn_update_dpp(0, __float_as_int(v), 0x111, 0xF, 0xF, true);  v += __int_as_float(t);
    t = __builtin_amdgcn_update_dpp(0, __float_as_int(v), 0x112, 0xF, 0xF, true);  v += __int_as_float(t);
    t = __builtin_amdgcn_update_dpp(0, __float_as_int(v), 0x114, 0xF, 0xF, true);  v += __int_as_float(t);
    t = __builtin_amdgcn_update_dpp(0, __float_as_int(v), 0x118, 0xF, 0xF, true);  v += __int_as_float(t);
    t = __builtin_amdgcn_update_dpp(0, __float_as_int(v), 0x142, 0xA, 0xF, false); v += __int_as_float(t);
    t = __builtin_amdgcn_update_dpp(0, __float_as_int(v), 0x143, 0xC, 0xF, false); v += __int_as_float(t);
    return __int_as_float(__builtin_amdgcn_readlane(__float_as_int(v), 63));
}

// per-half sums: sA = sum lanes 0..31, sB = sum lanes 32..63 (one 5-stage reduction)
__device__ __forceinline__ void half_sums_f32(float v, float* sA, float* sB) {
    int t;
    t = __builtin_amdgcn_update_dpp(0, __float_as_int(v), 0x111, 0xF, 0xF, true);  v += __int_as_float(t);
    t = __builtin_amdgcn_update_dpp(0, __float_as_int(v), 0x112, 0xF, 0xF, true);  v += __int_as_float(t);
    t = __builtin_amdgcn_update_dpp(0, __float_as_int(v), 0x114, 0xF, 0xF, true);  v += __int_as_float(t);
    t = __builtin_amdgcn_update_dpp(0, __float_as_int(v), 0x118, 0xF, 0xF, true);  v += __int_as_float(t);
    t = __builtin_amdgcn_update_dpp(0, __float_as_int(v), 0x142, 0xA, 0xF, false); v += __int_as_float(t); // bcast15 -> rows 1,3
    *sA = __int_as_float(__builtin_amdgcn_readlane(__float_as_int(v), 31));
    *sB = __int_as_float(__builtin_amdgcn_readlane(__float_as_int(v), 63));
}

// ---------------- Kernel 1: blank-normalized label probs ----------------
// One wave per (b, pair p). Lanes 0-31 load frame tA (float4 = full 512B row),
// lanes 32-63 load frame tB. One shared half-wave reduction; LDS b128 store;
// line-aligned 448B pe2 rows (lanes 51-55 write zero padding).
__global__ __launch_bounds__(256) void ctc_k1(
    const float* __restrict__ logits, const int* __restrict__ targets,
    ushort* __restrict__ pe2, float* __restrict__ logSb)
{
    const int wv = threadIdx.x >> 6, lane = threadIdx.x & 63;
    const int gp = blockIdx.x * 4 + wv;          // 0 .. BB*NP-1
    const int b = gp / NP, p = gp - b * NP;
    const int tA = 2 * p + 1, tB = 2 * p + 2;
    const bool vB = (tB < TT);

    const int trow = (lane < 32) ? tA : (vB ? tB : tA);
    float4 x4 = reinterpret_cast<const float4*>(logits + ((size_t)b * TT + trow) * VV)[lane & 31];

    float e0 = __expf(x4.x), e1 = __expf(x4.y);
    float e2 = __expf(x4.z), e3 = __expf(x4.w);
    float sa, sb;
    half_sums_f32((e0 + e1) + (e2 + e3), &sa, &sb);

    __shared__ float sm[4][2][VV];
    {
        float4 ev; ev.x = e0; ev.y = e1; ev.z = e2; ev.w = e3;
        *reinterpret_cast<float4*>(&sm[wv][lane >> 5][(lane & 31) * 4]) = ev;
    }
    // producer and consumer are the SAME wave: no barrier needed

    int tg0 = 0, tg1 = 0;
    if (lane < 50) {
        int2 tg = reinterpret_cast<const int2*>(targets)[b * (SS / 2) + lane];
        tg0 = tg.x; tg1 = tg.y;
    }
    const float qiA = 1.0f / sm[wv][0][0];
    const float qiB = 1.0f / sm[wv][1][0];           // when !vB this is row A again (unused)
    float q1a = 0.f, q3a = 0.f, q1b = 0.f, q3b = 0.f;
    if (lane < 50) {                                  // slots 4l+1, 4l+3 <= 199 < 201
        q1a = fminf(sm[wv][0][tg0] * qiA, 65504.f);
        q3a = fminf(sm[wv][0][tg1] * qiA, 65504.f);
        if (vB) {
            q1b = fminf(sm[wv][1][tg0] * qiB, 65504.f);
            q3b = fminf(sm[wv][1][tg1] * qiB, 65504.f);
        }
    }
    if (lane < 56) {                                  // 56*8 = 448B: full 7-line row, zero padded
        ushort4 w;
        w.x = __half_as_ushort(__float2half_rn(q1a));
        w.y = __half_as_ushort(__float2half_rn(q3a));
        w.z = __half_as_ushort(__float2half_rn(q1b));
        w.w = __half_as_ushort(__float2half_rn(q3b));
        *reinterpret_cast<ushort4*>((char*)pe2 + ((size_t)b * NP + p) * PRB + lane * 8) = w;
    }
    if (lane == 0) {
        float xB0 = __int_as_float(__builtin_amdgcn_readlane(__float_as_int(x4.x), 32));
        logSb[b * TT + tA] = __logf(sa) - x4.x;
        if (vB) logSb[b * TT + tB] = __logf(sb) - xB0;
    }
}

// ---------------- Kernel 2: bidirectional scan, 2 waves per batch (round-6 form) ----------------
union H4 { uint2 u; __half h[4]; };

__device__ __forceinline__ double dpp_shr1_f64(double x) {   // lane l <- l-1, lane0 -> 0
    long long bl = __double_as_longlong(x);
    int lo = (int)bl, hi = (int)(bl >> 32);
    lo = __builtin_amdgcn_update_dpp(0, lo, 0x138, 0xF, 0xF, true);  // wave_shr:1
    hi = __builtin_amdgcn_update_dpp(0, hi, 0x138, 0xF, 0xF, true);
    return __longlong_as_double((long long)(((unsigned long long)(unsigned)hi << 32) | (unsigned)lo));
}

__device__ __forceinline__ double dpp_shl1_f64(double x) {   // lane l <- l+1, lane63 -> 0
    long long bl = __double_as_longlong(x);
    int lo = (int)bl, hi = (int)(bl >> 32);
    lo = __builtin_amdgcn_update_dpp(0, lo, 0x130, 0xF, 0xF, true);  // wave_shl:1
    hi = __builtin_amdgcn_update_dpp(0, hi, 0x130, 0xF, 0xF, true);
    return __longlong_as_double((long long)(((unsigned long long)(unsigned)hi << 32) | (unsigned)lo));
}

__device__ __forceinline__ int wave_max_i32(int v) {
    int t;
    t = __builtin_amdgcn_update_dpp(0, v, 0x111, 0xF, 0xF, true); v = v > t ? v : t;
    t = __builtin_amdgcn_update_dpp(0, v, 0x112, 0xF, 0xF, true); v = v > t ? v : t;
    t = __builtin_amdgcn_update_dpp(0, v, 0x114, 0xF, 0xF, true); v = v > t ? v : t;
    t = __builtin_amdgcn_update_dpp(0, v, 0x118, 0xF, 0xF, true); v = v > t ? v : t;
    t = __builtin_amdgcn_update_dpp(v, v, 0x142, 0xA, 0xF, false); v = v > t ? v : t;
    t = __builtin_amdgcn_update_dpp(v, v, 0x143, 0xC, 0xF, false); v = v > t ? v : t;
    return __builtin_amdgcn_readlane(v, 63);
}

#define FSTEP(Q1, Q3) do {                                   \
    double am1 = dpp_shr1_f64(a3);                           \
    double t23 = a2 + a3;                                    \
    double n3 = fma(sk3, a1, t23) * (Q3);                    \
    double t01 = a0 + a1;                                    \
    double n1 = fma(sk1, am1, t01) * (Q1);                   \
    double n0 = a0 + am1;                                    \
    double n2 = a1 + a2;                                     \
    a0 = n0; a1 = n1; a2 = n2; a3 = n3;                      \
} while (0)

#define BSTEP(Q1, Q3) do {                                   \
    double bp0 = dpp_shl1_f64(a0);                           \
    double bp1 = dpp_shl1_f64(a1);                           \
    double t12 = a1 + a2;                                    \
    double c1 = fma(sk3, a3, t12) * (Q1);                    \
    double c0 = a0 + a1;                                     \
    double t30 = a3 + bp0;                                   \
    double c3 = fma(skB, bp1, t30) * (Q3);                   \
    double c2 = a2 + a3;                                     \
    a0 = c0; a1 = c1; a2 = c2; a3 = c3;                      \
} while (0)

#define RENORM() do {                                        \
    int h0 = (int)(__double_as_longlong(a0) >> 32);          \
    int h1 = (int)(__double_as_longlong(a1) >> 32);          \
    int h2 = (int)(__double_as_longlong(a2) >> 32);          \
    int h3 = (int)(__double_as_longlong(a3) >> 32);          \
    int m01 = h0 > h1 ? h0 : h1;                             \
    int m23 = h2 > h3 ? h2 : h3;                             \
    int mm  = wave_max_i32(m01 > m23 ? m01 : m23);           \
    int ex  = (mm >> 20) & 0x7FF;                            \
    int exc = ex > 0 ? ex : 1;                               \
    double f = __longlong_as_double((long long)(2046 - exc) << 52); \
    a0 *= f; a1 *= f; a2 *= f; a3 *= f;                      \
    Epow += exc - 1023;                                      \
} while (0)

#define CVT4(H, Q1A, Q3A, Q1B, Q3B) do {                     \
    Q1A = (double)__half2float((H).h[0]);                    \
    Q3A = (double)__half2float((H).h[1]);                    \
    Q1B = (double)__half2float((H).h[2]);                    \
    Q3B = (double)__half2float((H).h[3]); } while (0)

__global__ __launch_bounds__(128) void ctc_k2(
    const float* __restrict__ logits, const ushort* __restrict__ pe2,
    const float* __restrict__ logSb, const int* __restrict__ targets,
    const int* __restrict__ in_lens, const int* __restrict__ tgt_lens,
    float* __restrict__ out)
{
    const int b    = blockIdx.x;
    const int tid  = threadIdx.x;
    const int wv   = tid >> 6;          // 0 = forward (alpha), 1 = backward (beta)
    const int lane = tid & 63;
    const int n    = in_lens[b];
    const int tl   = tgt_lens[b];

    const int P  = (13 * (n - 2)) / 50;     // forward pairs (frames 1..2P)
    const int pL = (n - 2) >> 1;            // pair containing frame n-1

    __shared__ double SA[256];
    __shared__ double SC[256];
    __shared__ double sred[2];
    __shared__ int    sE[2];

    int tg0 = 0, tg1 = 0, tgm1 = 0, tg2 = 0;
    if (lane < 50) {
        int2 tg = reinterpret_cast<const int2*>(targets)[b * (SS / 2) + lane];
        tg0 = tg.x; tg1 = tg.y;
    }
    if (lane >= 1 && lane <= 50) tgm1 = targets[b * SS + 2 * lane - 1];
    if (lane <= 48) tg2 = targets[b * SS + 2 * lane + 2];
    const double sk1 = (tg0 != tgm1) ? 1.0 : 0.0;   // fwd: slot 4l+1 <- 4l-1
    const double sk3 = (tg1 != tg0)  ? 1.0 : 0.0;   // fwd: 4l+3 <- 4l+1; bwd: 4l+1 <- 4l+3
    const double skB = (tg2 != tg1)  ? 1.0 : 0.0;   // bwd: slot 4l+3 <- 4l+5

    const int cl = (lane < 51) ? lane : 50;
    const char* PBbase = (const char*)pe2 + (size_t)b * NP * PRB + (size_t)cl * 8;

    double a0 = 0.0, a1 = 0.0, a2 = 0.0, a3 = 0.0;
    int Epow = 0;
    double lsb0 = 0.0;
    uint2 buf[16];

    if (wv == 0) {
        // frame-0 prologue from logits
        float2 x0 = reinterpret_cast<const float2*>(logits + (size_t)b * TT * VV)[lane];
        float e00 = __expf(x0.x), e01 = __expf(x0.y);
        float s0v = wave_sum_f32(e00 + e01);
        float qb0 = __shfl(e00, 0);
        int ext1 = targets[b * SS];                      // first label (uniform)
        float qn = __shfl((ext1 & 1) ? e01 : e00, ext1 >> 1);
        if (lane == 0) {
            a0 = 1.0;
            if (tl > 0) a1 = (double)qn / (double)qb0;
            lsb0 = (double)__logf(s0v) - (double)x0.x;
        }

        // forward pairs 0 .. P-1 (frames 1..2P), cvt pipelined 1 pair ahead
        #pragma unroll
        for (int d = 0; d < 16; ++d)
            buf[d] = *reinterpret_cast<const uint2*>(PBbase + (size_t)d * PRB);
        const char* Pc = PBbase + (size_t)16 * PRB;
        double c1A, c3A, c1B, c3B, n1A, n3A, n1B, n3B;
        { H4 h0; h0.u = buf[0]; CVT4(h0, c1A, c3A, c1B, c3B); }
        const int nfull = P >> 4, rem = P & 15;
        for (int c = 0; c < nfull; ++c) {
            #pragma unroll
            for (int d = 0; d < 16; ++d) {
                H4 hn; hn.u = buf[(d + 1) & 15];
                buf[d] = *reinterpret_cast<const uint2*>(Pc + (size_t)d * PRB);
                CVT4(hn, n1A, n3A, n1B, n3B);
                FSTEP(c1A, c3A);
                FSTEP(c1B, c3B);
                c1A = n1A; c3A = n3A; c1B = n1B; c3B = n3B;
            }
            RENORM();
            Pc += (size_t)16 * PRB;
        }
        #pragma unroll
        for (int d = 0; d < 16; ++d) {
            if (d < rem) {
                H4 h; h.u = buf[d];
                double q1A, q3A, q1B, q3B; CVT4(h, q1A, q3A, q1B, q3B);
                FSTEP(q1A, q3A);
                FSTEP(q1B, q3B);
            }
        }
        RENORM();
        SA[4 * lane + 0] = a0; SA[4 * lane + 1] = a1;
        SA[4 * lane + 2] = a2; SA[4 * lane + 3] = a3;
        if (lane == 0) sE[0] = Epow;
    } else {
        // backward init at frame n-1 (from pair pL)
        H4 hi; hi.u = *reinterpret_cast<const uint2*>(PBbase + (size_t)pL * PRB);
        const bool nOdd = (n & 1);
        double q1i = (double)__half2float(nOdd ? hi.h[2] : hi.h[0]);
        double q3i = (double)__half2float(nOdd ? hi.h[3] : hi.h[1]);
        const int s2 = 2 * tl, s1 = 2 * tl - 1;
        a0 = (4 * lane     == s2) ? 1.0 : 0.0;
        a1 = (4 * lane + 1 == s1) ? q1i : 0.0;
        a2 = (4 * lane + 2 == s2) ? 1.0 : 0.0;
        a3 = (4 * lane + 3 == s1) ? q3i : 0.0;
        if (nOdd) {   // extra step for frame n-2 = tA of pair pL
            double q1 = (double)__half2float(hi.h[0]);
            double q3 = (double)__half2float(hi.h[1]);
            BSTEP(q1, q3);
        }

        const int NB = pL - P;
        #pragma unroll
        for (int d = 0; d < 16; ++d)
            buf[d] = *reinterpret_cast<const uint2*>(PBbase + (size_t)(pL - 1 - d) * PRB);
        const char* Pc = PBbase + (size_t)(pL - 1 - 16) * PRB;
        double c1A, c3A, c1B, c3B, n1A, n3A, n1B, n3B;
        { H4 h0; h0.u = buf[0]; CVT4(h0, c1A, c3A, c1B, c3B); }
        const int nfull = NB >> 4, rem = NB & 15;
        for (int c = 0; c < nfull; ++c) {
            #pragma unroll
            for (int d = 0; d < 16; ++d) {
                H4 hn; hn.u = buf[(d + 1) & 15];
                buf[d] = *reinterpret_cast<const uint2*>(Pc - (size_t)d * PRB);
                CVT4(hn, n1A, n3A, n1B, n3B);
                BSTEP(c1B, c3B);     // frame tB first (higher t)
                BSTEP(c1A, c3A);
                c1A = n1A; c3A = n3A; c1B = n1B; c3B = n3B;
            }
            RENORM();
            Pc -= (size_t)16 * PRB;
        }
        #pragma unroll
        for (int d = 0; d < 16; ++d) {
            if (d < rem) {
                H4 h; h.u = buf[d];
                double q1A, q3A, q1B, q3B; CVT4(h, q1A, q3A, q1B, q3B);
                BSTEP(q1B, q3B);
                BSTEP(q1A, q3A);
            }
        }
        RENORM();
        // final shift-add (no q): C = betaX at frame 2P
        {
            double bp0 = dpp_shl1_f64(a0);
            double bp1 = dpp_shl1_f64(a1);
            double c0 = a0 + a1;
            double c1 = fma(sk3, a3, a1 + a2);
            double c2 = a2 + a3;
            double c3 = fma(skB, bp1, a3 + bp0);
            SC[4 * lane + 0] = c0; SC[4 * lane + 1] = c1;
            SC[4 * lane + 2] = c2; SC[4 * lane + 3] = c3;
        }
        if (lane == 0) sE[1] = Epow;
    }

    // logSb partial sums over frames 1..n-1, strided across all 128 threads
    double cb = 0.0;
    for (int t = 1 + tid; t < n; t += 128) cb += (double)logSb[b * TT + t];
    #pragma unroll
    for (int off = 32; off; off >>= 1) cb += __shfl_xor(cb, off);
    if (lane == 0) sred[wv] = cb;

    __syncthreads();

    if (wv == 0) {
        double d0 = SA[4 * lane + 0] * SC[4 * lane + 0]
                  + SA[4 * lane + 1] * SC[4 * lane + 1]
                  + SA[4 * lane + 2] * SC[4 * lane + 2]
                  + SA[4 * lane + 3] * SC[4 * lane + 3];
        #pragma unroll
        for (int off = 32; off; off >>= 1) d0 += __shfl_xor(d0, off);
        if (lane == 0) {
            double dot = d0;
            int extraE = 0;
            long long bits = __double_as_longlong(dot);
            int be = (int)((bits >> 52) & 0x7FF);
            if (be == 0) {                 // denormal rescue
                dot *= 0x1.0p+512;
                bits = __double_as_longlong(dot);
                be = (int)((bits >> 52) & 0x7FF);
                extraE = -512;
            }
            double mant = __longlong_as_double((bits & 0xFFFFFFFFFFFFFLL) | 0x3FF0000000000000LL);
            double logdot = ((double)(be - 1023 + extraE + sE[0] + sE[1])) * LN2D
                          + (double)__logf((float)mant);
            double loss = (sred[0] + sred[1] + lsb0) - logdot;
            atomicAdd(out, (float)loss);
        }
    }
}

extern "C" void kernel_launch(void* const* d_in, const int* in_sizes, int n_in,
                              void* d_out, int out_size, void* d_ws, size_t ws_size,
                              hipStream_t stream)
{
    const float* logits  = (const float*)d_in[0];
    const int* targets   = (const int*)d_in[1];
    const int* in_lens   = (const int*)d_in[2];
    const int* tgt_lens  = (const int*)d_in[3];
    float* out = (float*)d_out;

    ushort* pe2 = (ushort*)d_ws;                                     // 64*1000*448 = 28,672,000 B
    float* logSb = (float*)((char*)d_ws + (size_t)BB * NP * PRB);    // +512,000 B

    hipMemsetAsync(d_out, 0, sizeof(float), stream);
    ctc_k1<<<BB * NP / 4, 256, 0, stream>>>(logits, targets, pe2, logSb);
    ctc_k2<<<BB, 128, 0, stream>>>(logits, pe2, logSb, targets, in_lens, tgt_lens, out);
}